// Round 10
// baseline (68.018 us; speedup 1.0000x reference)
//
#include <hip/hip_runtime.h>
#include <cmath>

namespace {

typedef short short8 __attribute__((ext_vector_type(8)));
typedef float f32x4  __attribute__((ext_vector_type(4)));
typedef unsigned short ushort;

constexpr int HID  = 128;
constexpr int QP   = 1024;   // Q*P
constexpr int N    = 64;
constexpr int NPTS = 4096;   // N*N
constexpr int B    = 16;
constexpr int P    = 32;
constexpr int Q    = 32;
constexpr int LDH  = 136;    // mlp h LDS stride (bf16)
constexpr int CH   = 4;      // contract c-split factor
constexpr int CCH  = P / CH; // 8 c per contract block

__device__ __forceinline__ ushort f2bf(float x) {
    unsigned u = __float_as_uint(x);
    u += 0x7FFF + ((u >> 16) & 1);          // round-to-nearest-even
    return (ushort)(u >> 16);
}
__device__ __forceinline__ float bf2f(ushort b) {
    return __uint_as_float((unsigned)b << 16);
}
__device__ __forceinline__ float gelu_tanh(float x) {
    const float c0 = 0.7978845608028654f;   // sqrt(2/pi)
    const float c1 = 0.044715f;
    float inner = c0 * (x + c1 * x * x * x);
    return 0.5f * x * (1.0f + tanhf(inner));
}
__device__ __forceinline__ void gll16(const ushort* src, ushort* dst) {
    __builtin_amdgcn_global_load_lds(
        (const __attribute__((address_space(1))) unsigned int*)src,
        (__attribute__((address_space(3))) unsigned int*)dst, 16, 0, 0);
}

// ---------------------------------------------------------------------------
// Kernel 0: prep = wsplit (blocks [0,1152)) + ucvt (blocks [1152,3200)).
// ---------------------------------------------------------------------------
__global__ __launch_bounds__(256)
void prep_kernel(const float* __restrict__ W1a, const float* __restrict__ W2a,
                 const float* __restrict__ W1b, const float* __restrict__ W2b,
                 const float* __restrict__ u,
                 ushort* __restrict__ W1Th, ushort* __restrict__ W1Tl,
                 ushort* __restrict__ W2Th, ushort* __restrict__ W2Tl,
                 ushort* __restrict__ ubf)
{
    const int bid = blockIdx.x;
    if (bid < 1152) {
        const int g   = bid * 256 + threadIdx.x;   // 0 .. 2*147456-1
        const int dim = g / 147456;
        const int r   = g - dim * 147456;
        const float* W1 = dim ? W1b : W1a;
        const float* W2 = dim ? W2b : W2a;
        float v; ushort *dh, *dl; int idx;
        if (r < 16384) {                 // W1T
            const int o = r >> 7, k = r & 127;
            v = W1[k * HID + o];
            idx = dim * 16384 + r;
            dh = W1Th; dl = W1Tl;
        } else {                          // W2T
            const int r2 = r - 16384;
            const int o = r2 >> 7, k = r2 & 127;
            v = W2[k * QP + o];
            idx = dim * 131072 + r2;
            dh = W2Th; dl = W2Tl;
        }
        const ushort h = f2bf(v);
        const ushort l = f2bf(v - bf2f(h));
        dh[idx] = h; dl[idx] = l;
    } else {
        const int g = (bid - 1152) * 256 + threadIdx.x;   // float4 index
        const float4 v = reinterpret_cast<const float4*>(u)[g];
        uint2 pk;
        pk.x = (unsigned)f2bf(v.x) | ((unsigned)f2bf(v.y) << 16);
        pk.y = (unsigned)f2bf(v.z) | ((unsigned)f2bf(v.w) << 16);
        reinterpret_cast<uint2*>(ubf)[g] = pk;
    }
}

// ---------------------------------------------------------------------------
// Kernel 1: MLP via 2-term split-bf16 MFMA (weights split h+l, activations
// bf16-only). LDS 34.8 KB -> 2 blocks/CU. o-half z-axis (known-good R6 form).
// Quadrature fold: K1w = K1 * w1[col], K2w = K2 * w2[col].
// ---------------------------------------------------------------------------
__global__ __launch_bounds__(256, 2)
void mlp_kernel(const float* __restrict__ xs1, const float* __restrict__ xs2,
                const float* __restrict__ W0a, const float* __restrict__ b0a,
                const float* __restrict__ b1a, const float* __restrict__ b2a,
                const float* __restrict__ W0b, const float* __restrict__ b0b,
                const float* __restrict__ b1b, const float* __restrict__ b2b,
                const ushort* __restrict__ W1Th, const ushort* __restrict__ W1Tl,
                const ushort* __restrict__ W2Th, const ushort* __restrict__ W2Tl,
                const float* __restrict__ qw1, const float* __restrict__ qw2,
                ushort* __restrict__ K1out, ushort* __restrict__ K2out)
{
    __shared__ ushort h0h[N * LDH];
    __shared__ ushort h1h[N * LDH];

    const int i   = blockIdx.x;       // grid row
    const int dim = blockIdx.y;
    const int bz  = blockIdx.z;       // o-half
    const float* xs = dim ? xs2 : xs1;
    const float* W0 = dim ? W0b : W0a;
    const float* b0 = dim ? b0b : b0a;
    const float* b1 = dim ? b1b : b1a;
    const float* b2 = dim ? b2b : b2a;
    const float* wq = dim ? qw2 : qw1;
    const ushort* w1h = W1Th + dim * 16384;
    const ushort* w1l = W1Tl + dim * 16384;
    const ushort* w2h = W2Th + dim * 131072;
    const ushort* w2l = W2Tl + dim * 131072;
    ushort* Kout = dim ? K2out : K1out;

    const int t  = threadIdx.x;
    const int w  = t >> 6;
    const int l  = t & 63;
    const int lr = l & 15;
    const int lh = l >> 4;
    const float y = xs[i];

    // ---- layer 0 (bf16 activations only) ----
    {
        const int ch    = t & 127;
        const int pbase = (t >> 7) * 32;
        const float wy = W0[ch], wx = W0[HID + ch], bb = b0[ch];
        for (int pp = 0; pp < 32; ++pp) {
            const int pt = pbase + pp;
            const float z = fmaf(y, wy, fmaf(xs[pt], wx, bb));
            h0h[pt * LDH + ch] = f2bf(gelu_tanh(z));
        }
    }
    __syncthreads();

    // ---- layer 1: 2-term split MFMA (Wh*h + Wl*h) ----
    {
        #pragma unroll
        for (int cc = 0; cc < 2; ++cc) {
            const int ct = w * 2 + cc;
            const ushort* ap = w1h + (ct * 16 + lr) * HID + lh * 8;
            const ushort* aq = w1l + (ct * 16 + lr) * HID + lh * 8;
            short8 Ah[4], Al[4];
            #pragma unroll
            for (int kk = 0; kk < 4; ++kk) {
                Ah[kk] = *reinterpret_cast<const short8*>(ap + kk * 32);
                Al[kk] = *reinterpret_cast<const short8*>(aq + kk * 32);
            }
            f32x4 acc[4];
            #pragma unroll
            for (int p = 0; p < 4; ++p) acc[p] = f32x4{0.f, 0.f, 0.f, 0.f};
            #pragma unroll
            for (int kk = 0; kk < 4; ++kk) {
                short8 Bh[4];
                #pragma unroll
                for (int p = 0; p < 4; ++p)
                    Bh[p] = *reinterpret_cast<const short8*>(&h0h[(p * 16 + lr) * LDH + kk * 32 + lh * 8]);
                #pragma unroll
                for (int p = 0; p < 4; ++p)
                    acc[p] = __builtin_amdgcn_mfma_f32_16x16x32_bf16(Ah[kk], Bh[p], acc[p], 0, 0, 0);
                #pragma unroll
                for (int p = 0; p < 4; ++p)
                    acc[p] = __builtin_amdgcn_mfma_f32_16x16x32_bf16(Al[kk], Bh[p], acc[p], 0, 0, 0);
            }
            const float4 bb = *reinterpret_cast<const float4*>(&b1[ct * 16 + lh * 4]);
            #pragma unroll
            for (int p = 0; p < 4; ++p) {
                ushort hb[4];
                #pragma unroll
                for (int r = 0; r < 4; ++r) {
                    const float zv = acc[p][r] + ((const float*)&bb)[r];
                    hb[r] = f2bf(gelu_tanh(zv));
                }
                uint2 ph;
                ph.x = (unsigned)hb[0] | ((unsigned)hb[1] << 16);
                ph.y = (unsigned)hb[2] | ((unsigned)hb[3] << 16);
                *reinterpret_cast<uint2*>(&h1h[(p * 16 + lr) * LDH + ct * 16 + lh * 4]) = ph;
            }
        }
    }
    __syncthreads();

    // ---- layer 2: 2-term (h*W2h + h*W2l), bias + quadrature fold ----
    {
        short8 Ah[4][4];
        #pragma unroll
        for (int p = 0; p < 4; ++p)
            #pragma unroll
            for (int kk = 0; kk < 4; ++kk)
                Ah[p][kk] = *reinterpret_cast<const short8*>(&h1h[(p * 16 + lr) * LDH + kk * 32 + lh * 8]);

        const int otbase = bz * 32 + w * 8;
        short8 BH[4], BL[4];

        #pragma unroll
        for (int oo = 0; oo < 8; ++oo) {
            const int OT = otbase + oo;
            const ushort* _p = w2h + (size_t)(OT * 16 + lr) * HID + lh * 8;
            const ushort* _q = w2l + (size_t)(OT * 16 + lr) * HID + lh * 8;
            #pragma unroll
            for (int kk = 0; kk < 4; ++kk) {
                BH[kk] = *reinterpret_cast<const short8*>(_p + kk * 32);
                BL[kk] = *reinterpret_cast<const short8*>(_q + kk * 32);
            }

            f32x4 acc[4];
            #pragma unroll
            for (int p = 0; p < 4; ++p) acc[p] = f32x4{0.f, 0.f, 0.f, 0.f};
            #pragma unroll
            for (int kk = 0; kk < 4; ++kk) {
                #pragma unroll
                for (int p = 0; p < 4; ++p)
                    acc[p] = __builtin_amdgcn_mfma_f32_16x16x32_bf16(Ah[p][kk], BH[kk], acc[p], 0, 0, 0);
                #pragma unroll
                for (int p = 0; p < 4; ++p)
                    acc[p] = __builtin_amdgcn_mfma_f32_16x16x32_bf16(Ah[p][kk], BL[kk], acc[p], 0, 0, 0);
            }

            const int _o = OT * 16 + lr;
            const float _bo = b2[_o];
            ushort* _d = Kout + (size_t)_o * NPTS + i * 64 + lh * 4;
            #pragma unroll
            for (int p = 0; p < 4; ++p) {
                const float4 _wv = *reinterpret_cast<const float4*>(wq + p * 16 + lh * 4);
                uint2 pk;
                pk.x = (unsigned)f2bf((acc[p][0] + _bo) * _wv.x) |
                       ((unsigned)f2bf((acc[p][1] + _bo) * _wv.y) << 16);
                pk.y = (unsigned)f2bf((acc[p][2] + _bo) * _wv.z) |
                       ((unsigned)f2bf((acc[p][3] + _bo) * _wv.w) << 16);
                *reinterpret_cast<uint2*>(_d + p * 16) = pk;
            }
        }
    }
}

// ---------------------------------------------------------------------------
// Kernel 2: contract — R6 hot loop + bf16 partial store (unchanged from R9).
// ---------------------------------------------------------------------------
__global__ __launch_bounds__(256, 2)
void contract_kernel(const ushort* __restrict__ ubf,
                     const ushort* __restrict__ K1,   // w1-folded
                     const ushort* __restrict__ K2,   // w2-folded
                     ushort* __restrict__ part)
{
    __shared__ ushort sK1[2][4096];
    __shared__ ushort sK2[2][4096];
    __shared__ ushort sZT[4][4096];

    // bijective XCD chunk swizzle: 512 = 8 * 64
    const int id0 = blockIdx.x;
    const int id  = (id0 & 7) * 64 + (id0 >> 3);
    const int bg  = id & 3;
    const int a   = (id >> 2) & 31;
    const int ch  = id >> 7;

    const int t  = threadIdx.x;
    const int w  = t >> 6;
    const int l  = t & 63;
    const int lr = l & 15;
    const int lh = l >> 4;
    const int b  = bg * 4 + w;
    const int c0 = ch * CCH;

    ushort* zt = &sZT[w][0];
    const int sc = (((l & 7) ^ (l >> 3)) << 3);
    const int r0 = 16 * w + (l >> 3);

#define STAGE(NB, CC) do {                                                      \
        const ushort* _k1 = K1 + (((size_t)a * P + (CC)) << 12);                \
        const ushort* _k2 = K2 + (((size_t)a * P + (CC)) << 12);                \
        gll16(_k1 + (r0    ) * 64 + sc, &sK1[NB][w * 1024      ]);              \
        gll16(_k1 + (r0 + 8) * 64 + sc, &sK1[NB][w * 1024 + 512]);              \
        gll16(_k2 + (r0    ) * 64 + sc, &sK2[NB][w * 1024      ]);              \
        gll16(_k2 + (r0 + 8) * 64 + sc, &sK2[NB][w * 1024 + 512]);              \
    } while (0)

#define LOAD_UF(UF, CC) do {                                                    \
        const ushort* _up = ubf + (((size_t)b * P + (CC)) << 12);               \
        _Pragma("unroll")                                                       \
        for (int jt = 0; jt < 4; ++jt)                                          \
            _Pragma("unroll")                                                   \
            for (int kk = 0; kk < 2; ++kk)                                      \
                UF[jt][kk] = *reinterpret_cast<const short8*>(                  \
                    _up + (16 * jt + lr) * 64 + kk * 32 + lh * 8);              \
    } while (0)

#define MM1(BUF, UF) do {                                                       \
        short8 Bf[4][2];                                                        \
        _Pragma("unroll")                                                       \
        for (int kt = 0; kt < 4; ++kt)                                          \
            _Pragma("unroll")                                                   \
            for (int kk = 0; kk < 2; ++kk)                                      \
                Bf[kt][kk] = *reinterpret_cast<const short8*>(                  \
                    &sK2[BUF][(16 * kt + lr) * 64 + (((kk * 4 + lh) ^ (lr & 7)) << 3)]); \
        _Pragma("unroll")                                                       \
        for (int jt = 0; jt < 4; ++jt)                                          \
            _Pragma("unroll")                                                   \
            for (int kt = 0; kt < 4; ++kt) zacc[jt][kt] = f32x4{0.f, 0.f, 0.f, 0.f}; \
        __builtin_amdgcn_s_setprio(1);                                          \
        _Pragma("unroll")                                                       \
        for (int kk = 0; kk < 2; ++kk)                                          \
            _Pragma("unroll")                                                   \
            for (int jt = 0; jt < 4; ++jt)                                      \
                _Pragma("unroll")                                               \
                for (int kt = 0; kt < 4; ++kt)                                  \
                    zacc[jt][kt] = __builtin_amdgcn_mfma_f32_16x16x32_bf16(     \
                        UF[jt][kk], Bf[kt][kk], zacc[jt][kt], 0, 0, 0);         \
        __builtin_amdgcn_s_setprio(0);                                          \
    } while (0)

#define ZTW() do {                                                              \
        _Pragma("unroll")                                                       \
        for (int kt = 0; kt < 4; ++kt) {                                        \
            const int rbase = (16 * kt + lr) * 64;                              \
            _Pragma("unroll")                                                   \
            for (int jt = 0; jt < 4; ++jt) {                                    \
                const f32x4 z = zacc[jt][kt];                                   \
                uint2 pk;                                                       \
                pk.x = (unsigned)f2bf(z[0]) | ((unsigned)f2bf(z[1]) << 16);     \
                pk.y = (unsigned)f2bf(z[2]) | ((unsigned)f2bf(z[3]) << 16);     \
                const int g = (2 * jt + (lh >> 1)) ^ (lr & 7);                  \
                *reinterpret_cast<uint2*>(&zt[rbase + (g << 3) + (lh & 1) * 4]) = pk; \
            }                                                                   \
        }                                                                       \
    } while (0)

#define MM2(BUF) do {                                                           \
        _Pragma("unroll")                                                       \
        for (int jj = 0; jj < 2; ++jj) {                                        \
            short8 A2[4], B2[4];                                                \
            _Pragma("unroll")                                                   \
            for (int it = 0; it < 4; ++it)                                      \
                A2[it] = *reinterpret_cast<const short8*>(                      \
                    &sK1[BUF][(16 * it + lr) * 64 + (((jj * 4 + lh) ^ (lr & 7)) << 3)]); \
            _Pragma("unroll")                                                   \
            for (int kt = 0; kt < 4; ++kt)                                      \
                B2[kt] = *reinterpret_cast<const short8*>(                      \
                    &zt[(16 * kt + lr) * 64 + (((jj * 4 + lh) ^ (lr & 7)) << 3)]); \
            __builtin_amdgcn_s_setprio(1);                                      \
            _Pragma("unroll")                                                   \
            for (int it = 0; it < 4; ++it)                                      \
                _Pragma("unroll")                                               \
                for (int kt = 0; kt < 4; ++kt)                                  \
                    oacc[it][kt] = __builtin_amdgcn_mfma_f32_16x16x32_bf16(     \
                        A2[it], B2[kt], oacc[it][kt], 0, 0, 0);                 \
            __builtin_amdgcn_s_setprio(0);                                      \
        }                                                                       \
    } while (0)

    f32x4 oacc[4][4];
    #pragma unroll
    for (int it = 0; it < 4; ++it)
        #pragma unroll
        for (int kt = 0; kt < 4; ++kt) oacc[it][kt] = f32x4{0.f, 0.f, 0.f, 0.f};
    f32x4 zacc[4][4];
    short8 UFa[4][2], UFb[4][2];

    // prologue
    STAGE(0, c0);
    LOAD_UF(UFa, c0);
    __syncthreads();

    #pragma unroll
    for (int cc = 0; cc < CCH; ++cc) {
        const int cur = cc & 1;
        if (cc + 1 < CCH) STAGE(cur ^ 1, c0 + cc + 1);
        if (cur == 0) {
            MM1(0, UFa);
            if (cc + 1 < CCH) LOAD_UF(UFb, c0 + cc + 1);
        } else {
            MM1(1, UFb);
            if (cc + 1 < CCH) LOAD_UF(UFa, c0 + cc + 1);
        }
        ZTW();
        asm volatile("s_waitcnt lgkmcnt(0)" ::: "memory");
        __builtin_amdgcn_sched_barrier(0);
        MM2(cur);
        __syncthreads();
    }

#undef STAGE
#undef LOAD_UF
#undef MM1
#undef ZTW
#undef MM2

    // ---- partial store (bf16): part[ch][b][a][i][k] ----
    ushort* pp = part + ((((size_t)ch * B + b) * Q + a) << 12);
    #pragma unroll
    for (int it = 0; it < 4; ++it)
        #pragma unroll
        for (int kt = 0; kt < 4; ++kt)
            #pragma unroll
            for (int r = 0; r < 4; ++r)
                pp[(16 * it + 4 * lh + r) * 64 + 16 * kt + lr] = f2bf(oacc[it][kt][r]);
}

// ---------------------------------------------------------------------------
// Kernel 3: sum the 4 bf16 c-split partials into fp32 out.
// ---------------------------------------------------------------------------
__global__ __launch_bounds__(256)
void addparts_kernel(const ushort* __restrict__ part, float* __restrict__ out)
{
    const int g = blockIdx.x * 256 + threadIdx.x;      // uint4 index (8 bf16)
    constexpr size_t SLAB = (size_t)B * Q * NPTS / 8;  // uint4 per slab
    const uint4* p = reinterpret_cast<const uint4*>(part);
    const uint4 s0 = p[g];
    const uint4 s1 = p[g + SLAB];
    const uint4 s2 = p[g + 2 * SLAB];
    const uint4 s3 = p[g + 3 * SLAB];
    float r[8];
    #pragma unroll
    for (int e = 0; e < 8; ++e) {
        const int wd = e >> 1, sh = (e & 1) * 16;
        const float v0 = bf2f((ushort)(((const unsigned*)&s0)[wd] >> sh));
        const float v1 = bf2f((ushort)(((const unsigned*)&s1)[wd] >> sh));
        const float v2 = bf2f((ushort)(((const unsigned*)&s2)[wd] >> sh));
        const float v3 = bf2f((ushort)(((const unsigned*)&s3)[wd] >> sh));
        r[e] = (v0 + v1) + (v2 + v3);
    }
    float4* o = reinterpret_cast<float4*>(out);
    o[g * 2]     = make_float4(r[0], r[1], r[2], r[3]);
    o[g * 2 + 1] = make_float4(r[4], r[5], r[6], r[7]);
}

} // namespace

extern "C" void kernel_launch(void* const* d_in, const int* in_sizes, int n_in,
                              void* d_out, int out_size, void* d_ws, size_t ws_size,
                              hipStream_t stream)
{
    const float* u     = (const float*)d_in[0];
    const float* x1    = (const float*)d_in[1];
    const float* x2    = (const float*)d_in[2];
    const float* w1    = (const float*)d_in[3];
    const float* w2    = (const float*)d_in[4];
    const float* k1W0  = (const float*)d_in[5];
    const float* k1b0  = (const float*)d_in[6];
    const float* k1W1  = (const float*)d_in[7];
    const float* k1b1  = (const float*)d_in[8];
    const float* k1W2  = (const float*)d_in[9];
    const float* k1b2  = (const float*)d_in[10];
    const float* k2W0  = (const float*)d_in[11];
    const float* k2b0  = (const float*)d_in[12];
    const float* k2W1  = (const float*)d_in[13];
    const float* k2b1  = (const float*)d_in[14];
    const float* k2W2  = (const float*)d_in[15];
    const float* k2b2  = (const float*)d_in[16];

    float* out = (float*)d_out;
    char* ws = (char*)d_ws;
    size_t off = 0;
    ushort* K1buf = (ushort*)(ws + off); off += (size_t)QP * NPTS * 2;         // 8 MB
    ushort* K2buf = (ushort*)(ws + off); off += (size_t)QP * NPTS * 2;         // 8 MB
    ushort* W2Th  = (ushort*)(ws + off); off += 2 * 131072 * 2;
    ushort* W2Tl  = (ushort*)(ws + off); off += 2 * 131072 * 2;
    ushort* W1Th  = (ushort*)(ws + off); off += 2 * 16384 * 2;
    ushort* W1Tl  = (ushort*)(ws + off); off += 2 * 16384 * 2;
    ushort* ubf   = (ushort*)(ws + off); off += (size_t)B * P * NPTS * 2;      // 4 MB
    ushort* part  = (ushort*)(ws + off); off += (size_t)CH * B * Q * NPTS * 2; // 16 MB

    prep_kernel<<<dim3(3200), 256, 0, stream>>>(
        k1W1, k1W2, k2W1, k2W2, u, W1Th, W1Tl, W2Th, W2Tl, ubf);

    mlp_kernel<<<dim3(64, 2, 2), 256, 0, stream>>>(
        x1, x2,
        k1W0, k1b0, k1b1, k1b2,
        k2W0, k2b0, k2b1, k2b2,
        W1Th, W1Tl, W2Th, W2Tl,
        w1, w2,
        K1buf, K2buf);

    contract_kernel<<<dim3(512), 256, 0, stream>>>(ubf, K1buf, K2buf, part);

    addparts_kernel<<<dim3((B * Q * NPTS) / (256 * 8)), 256, 0, stream>>>(part, out);
}

// Round 11
// 63.691 us; speedup vs baseline: 1.0679x; 1.0679x over previous
//
#include <hip/hip_runtime.h>
#include <cmath>

namespace {

typedef short short8 __attribute__((ext_vector_type(8)));
typedef float f32x4  __attribute__((ext_vector_type(4)));
typedef unsigned short ushort;

constexpr int HID  = 128;
constexpr int QP   = 1024;   // Q*P
constexpr int N    = 64;
constexpr int NPTS = 4096;   // N*N
constexpr int B    = 16;
constexpr int P    = 32;
constexpr int Q    = 32;
constexpr int LDH  = 136;    // mlp h LDS stride (bf16)
constexpr int CH   = 4;      // contract c-split factor
constexpr int CCH  = P / CH; // 8 c per contract block

__device__ __forceinline__ ushort f2bf(float x) {
    unsigned u = __float_as_uint(x);
    u += 0x7FFF + ((u >> 16) & 1);          // round-to-nearest-even
    return (ushort)(u >> 16);
}
__device__ __forceinline__ float bf2f(ushort b) {
    return __uint_as_float((unsigned)b << 16);
}
__device__ __forceinline__ float gelu_tanh(float x) {
    const float c0 = 0.7978845608028654f;   // sqrt(2/pi)
    const float c1 = 0.044715f;
    float inner = c0 * (x + c1 * x * x * x);
    return 0.5f * x * (1.0f + tanhf(inner));
}
__device__ __forceinline__ void gll16(const ushort* src, ushort* dst) {
    __builtin_amdgcn_global_load_lds(
        (const __attribute__((address_space(1))) unsigned int*)src,
        (__attribute__((address_space(3))) unsigned int*)dst, 16, 0, 0);
}

// ---------------------------------------------------------------------------
// Kernel 0: prep = wsplit (blocks [0,1152)) + ucvt (blocks [1152,3200)).
// ---------------------------------------------------------------------------
__global__ __launch_bounds__(256)
void prep_kernel(const float* __restrict__ W1a, const float* __restrict__ W2a,
                 const float* __restrict__ W1b, const float* __restrict__ W2b,
                 const float* __restrict__ u,
                 ushort* __restrict__ W1Th, ushort* __restrict__ W1Tl,
                 ushort* __restrict__ W2Th, ushort* __restrict__ W2Tl,
                 ushort* __restrict__ ubf)
{
    const int bid = blockIdx.x;
    if (bid < 1152) {
        const int g   = bid * 256 + threadIdx.x;   // 0 .. 2*147456-1
        const int dim = g / 147456;
        const int r   = g - dim * 147456;
        const float* W1 = dim ? W1b : W1a;
        const float* W2 = dim ? W2b : W2a;
        float v; ushort *dh, *dl; int idx;
        if (r < 16384) {                 // W1T
            const int o = r >> 7, k = r & 127;
            v = W1[k * HID + o];
            idx = dim * 16384 + r;
            dh = W1Th; dl = W1Tl;
        } else {                          // W2T
            const int r2 = r - 16384;
            const int o = r2 >> 7, k = r2 & 127;
            v = W2[k * QP + o];
            idx = dim * 131072 + r2;
            dh = W2Th; dl = W2Tl;
        }
        const ushort h = f2bf(v);
        const ushort l = f2bf(v - bf2f(h));
        dh[idx] = h; dl[idx] = l;
    } else {
        const int g = (bid - 1152) * 256 + threadIdx.x;   // float4 index
        const float4 v = reinterpret_cast<const float4*>(u)[g];
        uint2 pk;
        pk.x = (unsigned)f2bf(v.x) | ((unsigned)f2bf(v.y) << 16);
        pk.y = (unsigned)f2bf(v.z) | ((unsigned)f2bf(v.w) << 16);
        reinterpret_cast<uint2*>(ubf)[g] = pk;
    }
}

// ---------------------------------------------------------------------------
// Kernel 1: MLP via 2-term split-bf16 MFMA (weights h+l, activations bf16),
// WITH layer-2 1-deep B-prefetch (R6 structure) and no VGPR cap
// (launch_bounds(256,1): ~165 VGPR -> 8 waves/CU = 2 blocks/CU; LDS 34.8 KB).
// Quadrature fold: K1w = K1 * w1[col], K2w = K2 * w2[col].
// ---------------------------------------------------------------------------
__global__ __launch_bounds__(256, 1)
void mlp_kernel(const float* __restrict__ xs1, const float* __restrict__ xs2,
                const float* __restrict__ W0a, const float* __restrict__ b0a,
                const float* __restrict__ b1a, const float* __restrict__ b2a,
                const float* __restrict__ W0b, const float* __restrict__ b0b,
                const float* __restrict__ b1b, const float* __restrict__ b2b,
                const ushort* __restrict__ W1Th, const ushort* __restrict__ W1Tl,
                const ushort* __restrict__ W2Th, const ushort* __restrict__ W2Tl,
                const float* __restrict__ qw1, const float* __restrict__ qw2,
                ushort* __restrict__ K1out, ushort* __restrict__ K2out)
{
    __shared__ ushort h0h[N * LDH];
    __shared__ ushort h1h[N * LDH];

    const int i   = blockIdx.x;       // grid row
    const int dim = blockIdx.y;
    const int bz  = blockIdx.z;       // o-half
    const float* xs = dim ? xs2 : xs1;
    const float* W0 = dim ? W0b : W0a;
    const float* b0 = dim ? b0b : b0a;
    const float* b1 = dim ? b1b : b1a;
    const float* b2 = dim ? b2b : b2a;
    const float* wq = dim ? qw2 : qw1;
    const ushort* w1h = W1Th + dim * 16384;
    const ushort* w1l = W1Tl + dim * 16384;
    const ushort* w2h = W2Th + dim * 131072;
    const ushort* w2l = W2Tl + dim * 131072;
    ushort* Kout = dim ? K2out : K1out;

    const int t  = threadIdx.x;
    const int w  = t >> 6;
    const int l  = t & 63;
    const int lr = l & 15;
    const int lh = l >> 4;
    const float y = xs[i];

    // ---- layer 0 (bf16 activations only) ----
    {
        const int ch    = t & 127;
        const int pbase = (t >> 7) * 32;
        const float wy = W0[ch], wx = W0[HID + ch], bb = b0[ch];
        for (int pp = 0; pp < 32; ++pp) {
            const int pt = pbase + pp;
            const float z = fmaf(y, wy, fmaf(xs[pt], wx, bb));
            h0h[pt * LDH + ch] = f2bf(gelu_tanh(z));
        }
    }
    __syncthreads();

    // ---- layer 1: 2-term split MFMA (W1h*h + W1l*h) ----
    {
        #pragma unroll
        for (int cc = 0; cc < 2; ++cc) {
            const int ct = w * 2 + cc;
            const ushort* ap = w1h + (ct * 16 + lr) * HID + lh * 8;
            const ushort* aq = w1l + (ct * 16 + lr) * HID + lh * 8;
            short8 Ah[4], Al[4];
            #pragma unroll
            for (int kk = 0; kk < 4; ++kk) {
                Ah[kk] = *reinterpret_cast<const short8*>(ap + kk * 32);
                Al[kk] = *reinterpret_cast<const short8*>(aq + kk * 32);
            }
            f32x4 acc[4];
            #pragma unroll
            for (int p = 0; p < 4; ++p) acc[p] = f32x4{0.f, 0.f, 0.f, 0.f};
            #pragma unroll
            for (int kk = 0; kk < 4; ++kk) {
                short8 Bh[4];
                #pragma unroll
                for (int p = 0; p < 4; ++p)
                    Bh[p] = *reinterpret_cast<const short8*>(&h0h[(p * 16 + lr) * LDH + kk * 32 + lh * 8]);
                #pragma unroll
                for (int p = 0; p < 4; ++p)
                    acc[p] = __builtin_amdgcn_mfma_f32_16x16x32_bf16(Ah[kk], Bh[p], acc[p], 0, 0, 0);
                #pragma unroll
                for (int p = 0; p < 4; ++p)
                    acc[p] = __builtin_amdgcn_mfma_f32_16x16x32_bf16(Al[kk], Bh[p], acc[p], 0, 0, 0);
            }
            const float4 bb = *reinterpret_cast<const float4*>(&b1[ct * 16 + lh * 4]);
            #pragma unroll
            for (int p = 0; p < 4; ++p) {
                ushort hb[4];
                #pragma unroll
                for (int r = 0; r < 4; ++r) {
                    const float zv = acc[p][r] + ((const float*)&bb)[r];
                    hb[r] = f2bf(gelu_tanh(zv));
                }
                uint2 ph;
                ph.x = (unsigned)hb[0] | ((unsigned)hb[1] << 16);
                ph.y = (unsigned)hb[2] | ((unsigned)hb[3] << 16);
                *reinterpret_cast<uint2*>(&h1h[(p * 16 + lr) * LDH + ct * 16 + lh * 4]) = ph;
            }
        }
    }
    __syncthreads();

    // ---- layer 2: 2-term (h*W2h + h*W2l), 1-deep prefetch, fold epilogue ----
    {
        short8 Ah[4][4];
        #pragma unroll
        for (int p = 0; p < 4; ++p)
            #pragma unroll
            for (int kk = 0; kk < 4; ++kk)
                Ah[p][kk] = *reinterpret_cast<const short8*>(&h1h[(p * 16 + lr) * LDH + kk * 32 + lh * 8]);

        const int otbase = bz * 32 + w * 8;

#define LOADB(BH, BL, OT) do {                                                      \
        const ushort* _p = w2h + (size_t)((OT) * 16 + lr) * HID + lh * 8;           \
        const ushort* _q = w2l + (size_t)((OT) * 16 + lr) * HID + lh * 8;           \
        _Pragma("unroll")                                                           \
        for (int kk = 0; kk < 4; ++kk) {                                            \
            BH[kk] = *reinterpret_cast<const short8*>(_p + kk * 32);                \
            BL[kk] = *reinterpret_cast<const short8*>(_q + kk * 32);                \
        } } while (0)

#define MMTILE(BH, BL, OT) do {                                                     \
        f32x4 acc[4];                                                               \
        _Pragma("unroll")                                                           \
        for (int p = 0; p < 4; ++p) acc[p] = f32x4{0.f, 0.f, 0.f, 0.f};             \
        _Pragma("unroll")                                                           \
        for (int kk = 0; kk < 4; ++kk) {                                            \
            _Pragma("unroll")                                                       \
            for (int p = 0; p < 4; ++p)                                             \
                acc[p] = __builtin_amdgcn_mfma_f32_16x16x32_bf16(Ah[p][kk], BH[kk], acc[p], 0, 0, 0); \
            _Pragma("unroll")                                                       \
            for (int p = 0; p < 4; ++p)                                             \
                acc[p] = __builtin_amdgcn_mfma_f32_16x16x32_bf16(Ah[p][kk], BL[kk], acc[p], 0, 0, 0); \
        }                                                                           \
        const int _o = (OT) * 16 + lr;                                              \
        const float _bo = b2[_o];                                                   \
        ushort* _d = Kout + (size_t)_o * NPTS + i * 64 + lh * 4;                    \
        _Pragma("unroll")                                                           \
        for (int p = 0; p < 4; ++p) {                                               \
            const float4 _wv = *reinterpret_cast<const float4*>(wq + p * 16 + lh * 4); \
            uint2 pk;                                                               \
            pk.x = (unsigned)f2bf((acc[p][0] + _bo) * _wv.x) |                      \
                   ((unsigned)f2bf((acc[p][1] + _bo) * _wv.y) << 16);               \
            pk.y = (unsigned)f2bf((acc[p][2] + _bo) * _wv.z) |                      \
                   ((unsigned)f2bf((acc[p][3] + _bo) * _wv.w) << 16);               \
            *reinterpret_cast<uint2*>(_d + p * 16) = pk;                            \
        } } while (0)

        short8 B0h[4], B0l[4], B1h[4], B1l[4];
        LOADB(B0h, B0l, otbase + 0);
        #pragma unroll
        for (int oo = 0; oo < 8; oo += 2) {
            if (oo + 1 < 8) LOADB(B1h, B1l, otbase + oo + 1);
            MMTILE(B0h, B0l, otbase + oo);
            if (oo + 2 < 8) LOADB(B0h, B0l, otbase + oo + 2);
            MMTILE(B1h, B1l, otbase + oo + 1);
        }
#undef LOADB
#undef MMTILE
    }
}

// ---------------------------------------------------------------------------
// Kernel 2: contract — R6 hot loop + bf16 partial store (unchanged from R9).
// ---------------------------------------------------------------------------
__global__ __launch_bounds__(256, 2)
void contract_kernel(const ushort* __restrict__ ubf,
                     const ushort* __restrict__ K1,   // w1-folded
                     const ushort* __restrict__ K2,   // w2-folded
                     ushort* __restrict__ part)
{
    __shared__ ushort sK1[2][4096];
    __shared__ ushort sK2[2][4096];
    __shared__ ushort sZT[4][4096];

    // bijective XCD chunk swizzle: 512 = 8 * 64
    const int id0 = blockIdx.x;
    const int id  = (id0 & 7) * 64 + (id0 >> 3);
    const int bg  = id & 3;
    const int a   = (id >> 2) & 31;
    const int ch  = id >> 7;

    const int t  = threadIdx.x;
    const int w  = t >> 6;
    const int l  = t & 63;
    const int lr = l & 15;
    const int lh = l >> 4;
    const int b  = bg * 4 + w;
    const int c0 = ch * CCH;

    ushort* zt = &sZT[w][0];
    const int sc = (((l & 7) ^ (l >> 3)) << 3);
    const int r0 = 16 * w + (l >> 3);

#define STAGE(NB, CC) do {                                                      \
        const ushort* _k1 = K1 + (((size_t)a * P + (CC)) << 12);                \
        const ushort* _k2 = K2 + (((size_t)a * P + (CC)) << 12);                \
        gll16(_k1 + (r0    ) * 64 + sc, &sK1[NB][w * 1024      ]);              \
        gll16(_k1 + (r0 + 8) * 64 + sc, &sK1[NB][w * 1024 + 512]);              \
        gll16(_k2 + (r0    ) * 64 + sc, &sK2[NB][w * 1024      ]);              \
        gll16(_k2 + (r0 + 8) * 64 + sc, &sK2[NB][w * 1024 + 512]);              \
    } while (0)

#define LOAD_UF(UF, CC) do {                                                    \
        const ushort* _up = ubf + (((size_t)b * P + (CC)) << 12);               \
        _Pragma("unroll")                                                       \
        for (int jt = 0; jt < 4; ++jt)                                          \
            _Pragma("unroll")                                                   \
            for (int kk = 0; kk < 2; ++kk)                                      \
                UF[jt][kk] = *reinterpret_cast<const short8*>(                  \
                    _up + (16 * jt + lr) * 64 + kk * 32 + lh * 8);              \
    } while (0)

#define MM1(BUF, UF) do {                                                       \
        short8 Bf[4][2];                                                        \
        _Pragma("unroll")                                                       \
        for (int kt = 0; kt < 4; ++kt)                                          \
            _Pragma("unroll")                                                   \
            for (int kk = 0; kk < 2; ++kk)                                      \
                Bf[kt][kk] = *reinterpret_cast<const short8*>(                  \
                    &sK2[BUF][(16 * kt + lr) * 64 + (((kk * 4 + lh) ^ (lr & 7)) << 3)]); \
        _Pragma("unroll")                                                       \
        for (int jt = 0; jt < 4; ++jt)                                          \
            _Pragma("unroll")                                                   \
            for (int kt = 0; kt < 4; ++kt) zacc[jt][kt] = f32x4{0.f, 0.f, 0.f, 0.f}; \
        __builtin_amdgcn_s_setprio(1);                                          \
        _Pragma("unroll")                                                       \
        for (int kk = 0; kk < 2; ++kk)                                          \
            _Pragma("unroll")                                                   \
            for (int jt = 0; jt < 4; ++jt)                                      \
                _Pragma("unroll")                                               \
                for (int kt = 0; kt < 4; ++kt)                                  \
                    zacc[jt][kt] = __builtin_amdgcn_mfma_f32_16x16x32_bf16(     \
                        UF[jt][kk], Bf[kt][kk], zacc[jt][kt], 0, 0, 0);         \
        __builtin_amdgcn_s_setprio(0);                                          \
    } while (0)

#define ZTW() do {                                                              \
        _Pragma("unroll")                                                       \
        for (int kt = 0; kt < 4; ++kt) {                                        \
            const int rbase = (16 * kt + lr) * 64;                              \
            _Pragma("unroll")                                                   \
            for (int jt = 0; jt < 4; ++jt) {                                    \
                const f32x4 z = zacc[jt][kt];                                   \
                uint2 pk;                                                       \
                pk.x = (unsigned)f2bf(z[0]) | ((unsigned)f2bf(z[1]) << 16);     \
                pk.y = (unsigned)f2bf(z[2]) | ((unsigned)f2bf(z[3]) << 16);     \
                const int g = (2 * jt + (lh >> 1)) ^ (lr & 7);                  \
                *reinterpret_cast<uint2*>(&zt[rbase + (g << 3) + (lh & 1) * 4]) = pk; \
            }                                                                   \
        }                                                                       \
    } while (0)

#define MM2(BUF) do {                                                           \
        _Pragma("unroll")                                                       \
        for (int jj = 0; jj < 2; ++jj) {                                        \
            short8 A2[4], B2[4];                                                \
            _Pragma("unroll")                                                   \
            for (int it = 0; it < 4; ++it)                                      \
                A2[it] = *reinterpret_cast<const short8*>(                      \
                    &sK1[BUF][(16 * it + lr) * 64 + (((jj * 4 + lh) ^ (lr & 7)) << 3)]); \
            _Pragma("unroll")                                                   \
            for (int kt = 0; kt < 4; ++kt)                                      \
                B2[kt] = *reinterpret_cast<const short8*>(                      \
                    &zt[(16 * kt + lr) * 64 + (((jj * 4 + lh) ^ (lr & 7)) << 3)]); \
            __builtin_amdgcn_s_setprio(1);                                      \
            _Pragma("unroll")                                                   \
            for (int it = 0; it < 4; ++it)                                      \
                _Pragma("unroll")                                               \
                for (int kt = 0; kt < 4; ++kt)                                  \
                    oacc[it][kt] = __builtin_amdgcn_mfma_f32_16x16x32_bf16(     \
                        A2[it], B2[kt], oacc[it][kt], 0, 0, 0);                 \
            __builtin_amdgcn_s_setprio(0);                                      \
        }                                                                       \
    } while (0)

    f32x4 oacc[4][4];
    #pragma unroll
    for (int it = 0; it < 4; ++it)
        #pragma unroll
        for (int kt = 0; kt < 4; ++kt) oacc[it][kt] = f32x4{0.f, 0.f, 0.f, 0.f};
    f32x4 zacc[4][4];
    short8 UFa[4][2], UFb[4][2];

    // prologue
    STAGE(0, c0);
    LOAD_UF(UFa, c0);
    __syncthreads();

    #pragma unroll
    for (int cc = 0; cc < CCH; ++cc) {
        const int cur = cc & 1;
        if (cc + 1 < CCH) STAGE(cur ^ 1, c0 + cc + 1);
        if (cur == 0) {
            MM1(0, UFa);
            if (cc + 1 < CCH) LOAD_UF(UFb, c0 + cc + 1);
        } else {
            MM1(1, UFb);
            if (cc + 1 < CCH) LOAD_UF(UFa, c0 + cc + 1);
        }
        ZTW();
        asm volatile("s_waitcnt lgkmcnt(0)" ::: "memory");
        __builtin_amdgcn_sched_barrier(0);
        MM2(cur);
        __syncthreads();
    }

#undef STAGE
#undef LOAD_UF
#undef MM1
#undef ZTW
#undef MM2

    // ---- partial store (bf16): part[ch][b][a][i][k] ----
    ushort* pp = part + ((((size_t)ch * B + b) * Q + a) << 12);
    #pragma unroll
    for (int it = 0; it < 4; ++it)
        #pragma unroll
        for (int kt = 0; kt < 4; ++kt)
            #pragma unroll
            for (int r = 0; r < 4; ++r)
                pp[(16 * it + 4 * lh + r) * 64 + 16 * kt + lr] = f2bf(oacc[it][kt][r]);
}

// ---------------------------------------------------------------------------
// Kernel 3: sum the 4 bf16 c-split partials into fp32 out.
// ---------------------------------------------------------------------------
__global__ __launch_bounds__(256)
void addparts_kernel(const ushort* __restrict__ part, float* __restrict__ out)
{
    const int g = blockIdx.x * 256 + threadIdx.x;      // uint4 index (8 bf16)
    constexpr size_t SLAB = (size_t)B * Q * NPTS / 8;  // uint4 per slab
    const uint4* p = reinterpret_cast<const uint4*>(part);
    const uint4 s0 = p[g];
    const uint4 s1 = p[g + SLAB];
    const uint4 s2 = p[g + 2 * SLAB];
    const uint4 s3 = p[g + 3 * SLAB];
    float r[8];
    #pragma unroll
    for (int e = 0; e < 8; ++e) {
        const int wd = e >> 1, sh = (e & 1) * 16;
        const float v0 = bf2f((ushort)(((const unsigned*)&s0)[wd] >> sh));
        const float v1 = bf2f((ushort)(((const unsigned*)&s1)[wd] >> sh));
        const float v2 = bf2f((ushort)(((const unsigned*)&s2)[wd] >> sh));
        const float v3 = bf2f((ushort)(((const unsigned*)&s3)[wd] >> sh));
        r[e] = (v0 + v1) + (v2 + v3);
    }
    float4* o = reinterpret_cast<float4*>(out);
    o[g * 2]     = make_float4(r[0], r[1], r[2], r[3]);
    o[g * 2 + 1] = make_float4(r[4], r[5], r[6], r[7]);
}

} // namespace

extern "C" void kernel_launch(void* const* d_in, const int* in_sizes, int n_in,
                              void* d_out, int out_size, void* d_ws, size_t ws_size,
                              hipStream_t stream)
{
    const float* u     = (const float*)d_in[0];
    const float* x1    = (const float*)d_in[1];
    const float* x2    = (const float*)d_in[2];
    const float* w1    = (const float*)d_in[3];
    const float* w2    = (const float*)d_in[4];
    const float* k1W0  = (const float*)d_in[5];
    const float* k1b0  = (const float*)d_in[6];
    const float* k1W1  = (const float*)d_in[7];
    const float* k1b1  = (const float*)d_in[8];
    const float* k1W2  = (const float*)d_in[9];
    const float* k1b2  = (const float*)d_in[10];
    const float* k2W0  = (const float*)d_in[11];
    const float* k2b0  = (const float*)d_in[12];
    const float* k2W1  = (const float*)d_in[13];
    const float* k2b1  = (const float*)d_in[14];
    const float* k2W2  = (const float*)d_in[15];
    const float* k2b2  = (const float*)d_in[16];

    float* out = (float*)d_out;
    char* ws = (char*)d_ws;
    size_t off = 0;
    ushort* K1buf = (ushort*)(ws + off); off += (size_t)QP * NPTS * 2;         // 8 MB
    ushort* K2buf = (ushort*)(ws + off); off += (size_t)QP * NPTS * 2;         // 8 MB
    ushort* W2Th  = (ushort*)(ws + off); off += 2 * 131072 * 2;
    ushort* W2Tl  = (ushort*)(ws + off); off += 2 * 131072 * 2;
    ushort* W1Th  = (ushort*)(ws + off); off += 2 * 16384 * 2;
    ushort* W1Tl  = (ushort*)(ws + off); off += 2 * 16384 * 2;
    ushort* ubf   = (ushort*)(ws + off); off += (size_t)B * P * NPTS * 2;      // 4 MB
    ushort* part  = (ushort*)(ws + off); off += (size_t)CH * B * Q * NPTS * 2; // 16 MB

    prep_kernel<<<dim3(3200), 256, 0, stream>>>(
        k1W1, k1W2, k2W1, k2W2, u, W1Th, W1Tl, W2Th, W2Tl, ubf);

    mlp_kernel<<<dim3(64, 2, 2), 256, 0, stream>>>(
        x1, x2,
        k1W0, k1b0, k1b1, k1b2,
        k2W0, k2b0, k2b1, k2b2,
        W1Th, W1Tl, W2Th, W2Tl,
        w1, w2,
        K1buf, K2buf);

    contract_kernel<<<dim3(512), 256, 0, stream>>>(ubf, K1buf, K2buf, part);

    addparts_kernel<<<dim3((B * Q * NPTS) / (256 * 8)), 256, 0, stream>>>(part, out);
}